// Round 7
// baseline (679.289 us; speedup 1.0000x reference)
//
#include <hip/hip_runtime.h>

#define THREADS 320           // 5 waves; each wave owns 4 output rows
#define RB 20                 // output rows per block (3 bands x 20 = 60 exact)
#define IN_ROWS 24            // RB + 4 halo rows staged
#define PS 64                 // floats per staged LDS row
#define LDS_FLOATS (6 * IN_ROWS * PS)   // 9216 floats = 36864 B

// ---- named-scalar accumulators: NOTHING indexable, nothing can spill ----
#define DECL(OC) float A0_##OC = bias[OC], A1_##OC = bias[OC], \
                       A2_##OC = bias[OC], A3_##OC = bias[OC]

// load this ky's four input rows (output row r uses input row lr0+r+ky) for
// channel IC; one vaddr (brow) + compile-time DS immediates; lane-consecutive
#define LOADX(IC) do { \
    const float* p_ = brow + (IC) * (IN_ROWS * PS); \
    xa0 = p_[0];        xa1 = p_[1];        xa2 = p_[2];        xa3 = p_[3];        xa4 = p_[4]; \
    xb0 = p_[PS + 0];   xb1 = p_[PS + 1];   xb2 = p_[PS + 2];   xb3 = p_[PS + 3];   xb4 = p_[PS + 4]; \
    xc0 = p_[2*PS + 0]; xc1 = p_[2*PS + 1]; xc2 = p_[2*PS + 2]; xc3 = p_[2*PS + 3]; xc4 = p_[2*PS + 4]; \
    xd0 = p_[3*PS + 0]; xd1 = p_[3*PS + 1]; xd2 = p_[3*PS + 2]; xd3 = p_[3*PS + 3]; xd4 = p_[3*PS + 4]; \
} while (0)

// one (oc,ic) 5-tap group at the loop's ky: 5 uniform weight loads (scalar
// pipe), each weight feeds FOUR output rows -> 20 FMAs per load group
#define UPD4(OC, IC) do { \
    const float* wp_ = Wky + (OC) * 150 + (IC) * 25; \
    const float w0_ = wp_[0], w1_ = wp_[1], w2_ = wp_[2], w3_ = wp_[3], w4_ = wp_[4]; \
    A0_##OC = fmaf(xa0, w0_, A0_##OC);  A1_##OC = fmaf(xb0, w0_, A1_##OC); \
    A2_##OC = fmaf(xc0, w0_, A2_##OC);  A3_##OC = fmaf(xd0, w0_, A3_##OC); \
    A0_##OC = fmaf(xa1, w1_, A0_##OC);  A1_##OC = fmaf(xb1, w1_, A1_##OC); \
    A2_##OC = fmaf(xc1, w1_, A2_##OC);  A3_##OC = fmaf(xd1, w1_, A3_##OC); \
    A0_##OC = fmaf(xa2, w2_, A0_##OC);  A1_##OC = fmaf(xb2, w2_, A1_##OC); \
    A2_##OC = fmaf(xc2, w2_, A2_##OC);  A3_##OC = fmaf(xd2, w2_, A3_##OC); \
    A0_##OC = fmaf(xa3, w3_, A0_##OC);  A1_##OC = fmaf(xb3, w3_, A1_##OC); \
    A2_##OC = fmaf(xc3, w3_, A2_##OC);  A3_##OC = fmaf(xd3, w3_, A3_##OC); \
    A0_##OC = fmaf(xa4, w4_, A0_##OC);  A1_##OC = fmaf(xb4, w4_, A1_##OC); \
    A2_##OC = fmaf(xc4, w4_, A2_##OC);  A3_##OC = fmaf(xd4, w4_, A3_##OC); \
} while (0)

#define SBAR __builtin_amdgcn_sched_barrier(0)

// per input channel: its 10 connected output maps; SBAR caps the scheduler's
// hoisting window (~50 weights + 20 x values live max)
#define CHAN0 LOADX(0); UPD4(0,0);  UPD4(4,0);  UPD4(5,0);  UPD4(6,0);  UPD4(9,0);  UPD4(10,0); UPD4(11,0); UPD4(12,0); UPD4(14,0); UPD4(15,0); SBAR
#define CHAN1 LOADX(1); UPD4(0,1);  UPD4(1,1);  UPD4(5,1);  UPD4(6,1);  UPD4(7,1);  UPD4(10,1); UPD4(11,1); UPD4(12,1); UPD4(13,1); UPD4(15,1); SBAR
#define CHAN2 LOADX(2); UPD4(0,2);  UPD4(1,2);  UPD4(2,2);  UPD4(6,2);  UPD4(7,2);  UPD4(8,2);  UPD4(11,2); UPD4(13,2); UPD4(14,2); UPD4(15,2); SBAR
#define CHAN3 LOADX(3); UPD4(1,3);  UPD4(2,3);  UPD4(3,3);  UPD4(6,3);  UPD4(7,3);  UPD4(8,3);  UPD4(9,3);  UPD4(12,3); UPD4(14,3); UPD4(15,3); SBAR
#define CHAN4 LOADX(4); UPD4(2,4);  UPD4(3,4);  UPD4(4,4);  UPD4(7,4);  UPD4(8,4);  UPD4(9,4);  UPD4(10,4); UPD4(12,4); UPD4(13,4); UPD4(15,4); SBAR
#define CHAN5 LOADX(5); UPD4(3,5);  UPD4(4,5);  UPD4(5,5);  UPD4(8,5);  UPD4(9,5);  UPD4(10,5); UPD4(11,5); UPD4(13,5); UPD4(14,5); UPD4(15,5); SBAR

#define ST(T, OC) op[(OC) * 3600 + (T) * 60] = A##T##_##OC
#define STOC(OC) ST(0,OC); ST(1,OC); ST(2,OC); ST(3,OC)

__global__ __launch_bounds__(THREADS)
__attribute__((amdgpu_waves_per_eu(4, 4)))   // PIN allocator to 4 waves/EU = 128-VGPR budget
void c3_conv(const float* __restrict__ x, const float* __restrict__ W,
             const float* __restrict__ bias, float* __restrict__ out) {
    // +4 floats pad: lane 63's tap-4 read of the last staged row runs 3 past it
    __shared__ float xs[LDS_FLOATS + 4];

    const int blk  = blockIdx.x;
    const int img  = blk / 3;
    const int band = blk - img * 3;
    const int r0   = band * RB;
    const int t    = threadIdx.x;

    // ---- stage input tile: 6 ch x 24 rows x 64 cols, f32, float4 loads ----
    {
        const float4* src = reinterpret_cast<const float4*>(x) + (size_t)img * 6144;
        float4* dst = reinterpret_cast<float4*>(xs);
        #pragma unroll
        for (int k = 0; k < 8; ++k) {
            int s = t + k * THREADS;         // 0..2303 valid
            if (s < 6 * IN_ROWS * 16) {
                int ic  = s / (IN_ROWS * 16);        // 384 float4 per channel tile
                int rem = s - ic * (IN_ROWS * 16);
                int iy  = rem >> 4;
                int c4  = rem & 15;
                dst[s] = src[ic * 1024 + (r0 + iy) * 16 + c4];
            }
        }
    }
    __syncthreads();

    const int w    = t >> 6;                 // wave 0..4
    const int lr0  = 4 * w;                  // this wave's first output row (local)
    const int lane = t & 63;                 // lane = output column (0..59 valid)

    DECL(0);  DECL(1);  DECL(2);  DECL(3);  DECL(4);  DECL(5);  DECL(6);  DECL(7);
    DECL(8);  DECL(9);  DECL(10); DECL(11); DECL(12); DECL(13); DECL(14); DECL(15);

    float xa0, xa1, xa2, xa3, xa4;           // row lr0+ky+0
    float xb0, xb1, xb2, xb3, xb4;           // row lr0+ky+1
    float xc0, xc1, xc2, xc3, xc4;           // row lr0+ky+2
    float xd0, xd1, xd2, xd3, xd4;           // row lr0+ky+3

    // runtime ky loop bounds the scheduler window, keeps body ~6 KB (fits I$)
    #pragma unroll 1
    for (int ky = 0; ky < 5; ++ky) {
        const float* brow = xs + (lr0 + ky) * PS + lane;  // single vaddr per iter
        const float* Wky  = W + ky * 5;                   // uniform SGPR base
        CHAN0; CHAN1; CHAN2; CHAN3; CHAN4; CHAN5;
    }

    if (lane < 60) {
        float* op = out + (size_t)img * 57600 + (size_t)(r0 + lr0) * 60 + lane;
        STOC(0);  STOC(1);  STOC(2);  STOC(3);  STOC(4);  STOC(5);  STOC(6);  STOC(7);
        STOC(8);  STOC(9);  STOC(10); STOC(11); STOC(12); STOC(13); STOC(14); STOC(15);
    }
}

extern "C" void kernel_launch(void* const* d_in, const int* in_sizes, int n_in,
                              void* d_out, int out_size, void* d_ws, size_t ws_size,
                              hipStream_t stream) {
    const float* x  = (const float*)d_in[0];
    const float* W  = (const float*)d_in[1];
    const float* b  = (const float*)d_in[2];
    float* out      = (float*)d_out;

    const int nimg = in_sizes[0] / (6 * 64 * 64);   // 2048
    dim3 grid(nimg * 3), block(THREADS);
    hipLaunchKernelGGL(c3_conv, grid, block, 0, stream, x, W, b, out);
}

// Round 8
// 319.681 us; speedup vs baseline: 2.1249x; 2.1249x over previous
//
#include <hip/hip_runtime.h>

#define THREADS 384           // 6 waves; each wave owns 2 output rows
#define RB 12                 // output rows per block (5 bands x 12 = 60 exact)
#define IN_ROWS 16            // RB + 4 halo rows staged
#define PS 64                 // floats per staged LDS row
#define LDS_FLOATS (6 * IN_ROWS * PS)   // 6144 floats = 24576 B

// ---- named-scalar accumulators: NOTHING indexable, nothing can spill ----
#define DECL(OC) float A0_##OC = bias[OC], A1_##OC = bias[OC]

// load this ky's two input rows for channel IC; one vaddr (brow) +
// compile-time DS immediates; lane-consecutive -> conflict-free
#define LOADX(IC) do { \
    const float* p_ = brow + (IC) * (IN_ROWS * PS); \
    xa0 = p_[0];      xa1 = p_[1];      xa2 = p_[2];      xa3 = p_[3];      xa4 = p_[4]; \
    xb0 = p_[PS + 0]; xb1 = p_[PS + 1]; xb2 = p_[PS + 2]; xb3 = p_[PS + 3]; xb4 = p_[PS + 4]; \
} while (0)

// one (oc,ic) 5-tap group at the loop's ky: 5 uniform weight loads (scalar
// pipe), each weight feeds BOTH output rows
#define UPD2(OC, IC) do { \
    const float* wp_ = Wky + (OC) * 150 + (IC) * 25; \
    const float w0_ = wp_[0], w1_ = wp_[1], w2_ = wp_[2], w3_ = wp_[3], w4_ = wp_[4]; \
    A0_##OC = fmaf(xa0, w0_, A0_##OC);  A1_##OC = fmaf(xb0, w0_, A1_##OC); \
    A0_##OC = fmaf(xa1, w1_, A0_##OC);  A1_##OC = fmaf(xb1, w1_, A1_##OC); \
    A0_##OC = fmaf(xa2, w2_, A0_##OC);  A1_##OC = fmaf(xb2, w2_, A1_##OC); \
    A0_##OC = fmaf(xa3, w3_, A0_##OC);  A1_##OC = fmaf(xb3, w3_, A1_##OC); \
    A0_##OC = fmaf(xa4, w4_, A0_##OC);  A1_##OC = fmaf(xb4, w4_, A1_##OC); \
} while (0)

// Memory-permeable scheduling fence: VALU (0x2) may NOT cross (pins FMA order,
// caps accumulator live ranges) but SALU/SMEM (0x4), VMEM (0x10|0x20) and
// DS (0x80|0x100) MAY cross -> scheduler can prefetch next chan's weight
// s_loads and x ds_reads underneath this chan's ~1000-cycle FMA run.
#define SBAR __builtin_amdgcn_sched_barrier(0x4 | 0x10 | 0x20 | 0x80 | 0x100)

// per input channel: its 10 connected output maps
#define CHAN0 LOADX(0); UPD2(0,0);  UPD2(4,0);  UPD2(5,0);  UPD2(6,0);  UPD2(9,0);  UPD2(10,0); UPD2(11,0); UPD2(12,0); UPD2(14,0); UPD2(15,0); SBAR
#define CHAN1 LOADX(1); UPD2(0,1);  UPD2(1,1);  UPD2(5,1);  UPD2(6,1);  UPD2(7,1);  UPD2(10,1); UPD2(11,1); UPD2(12,1); UPD2(13,1); UPD2(15,1); SBAR
#define CHAN2 LOADX(2); UPD2(0,2);  UPD2(1,2);  UPD2(2,2);  UPD2(6,2);  UPD2(7,2);  UPD2(8,2);  UPD2(11,2); UPD2(13,2); UPD2(14,2); UPD2(15,2); SBAR
#define CHAN3 LOADX(3); UPD2(1,3);  UPD2(2,3);  UPD2(3,3);  UPD2(6,3);  UPD2(7,3);  UPD2(8,3);  UPD2(9,3);  UPD2(12,3); UPD2(14,3); UPD2(15,3); SBAR
#define CHAN4 LOADX(4); UPD2(2,4);  UPD2(3,4);  UPD2(4,4);  UPD2(7,4);  UPD2(8,4);  UPD2(9,4);  UPD2(10,4); UPD2(12,4); UPD2(13,4); UPD2(15,4); SBAR
#define CHAN5 LOADX(5); UPD2(3,5);  UPD2(4,5);  UPD2(5,5);  UPD2(8,5);  UPD2(9,5);  UPD2(10,5); UPD2(11,5); UPD2(13,5); UPD2(14,5); UPD2(15,5); SBAR

#define ST(T, OC) op[(OC) * 3600 + (T) * 60] = A##T##_##OC

__global__ __launch_bounds__(THREADS, 4)
void c3_conv(const float* __restrict__ x, const float* __restrict__ W,
             const float* __restrict__ bias, float* __restrict__ out) {
    // +4 floats pad: lane 63's tap-4 read of the last staged row runs past it
    __shared__ float xs[LDS_FLOATS + 4];

    const int blk  = blockIdx.x;
    const int img  = blk / 5;
    const int band = blk - img * 5;
    const int r0   = band * RB;
    const int t    = threadIdx.x;

    // ---- stage input tile: 6 ch x 16 rows x 64 cols, f32, float4 loads ----
    {
        const float4* src = reinterpret_cast<const float4*>(x) + (size_t)img * 6144;
        float4* dst = reinterpret_cast<float4*>(xs);
        #pragma unroll
        for (int k = 0; k < 4; ++k) {
            int s  = t + k * THREADS;        // 0..1535
            int ic = s >> 8;                 // 256 float4 per channel tile
            int iy = (s >> 4) & 15;
            int c4 = s & 15;
            dst[s] = src[ic * 1024 + (r0 + iy) * 16 + c4];
        }
    }
    __syncthreads();

    const int w    = t >> 6;                 // wave 0..5
    const int lr0  = 2 * w;                  // this wave's first output row (local)
    const int lane = t & 63;                 // lane = output column (0..59 valid)

    DECL(0);  DECL(1);  DECL(2);  DECL(3);  DECL(4);  DECL(5);  DECL(6);  DECL(7);
    DECL(8);  DECL(9);  DECL(10); DECL(11); DECL(12); DECL(13); DECL(14); DECL(15);

    float xa0, xa1, xa2, xa3, xa4;           // T0's input row for current ky
    float xb0, xb1, xb2, xb3, xb4;           // T1's input row for current ky

    // runtime ky loop bounds the scheduler window, keeps body ~5 KB (fits I$)
    #pragma unroll 1
    for (int ky = 0; ky < 5; ++ky) {
        const float* brow = xs + (lr0 + ky) * PS + lane;  // single vaddr per iter
        const float* Wky  = W + ky * 5;                   // uniform SGPR base
        CHAN0; CHAN1; CHAN2; CHAN3; CHAN4; CHAN5;
    }

    if (lane < 60) {
        float* op = out + (size_t)img * 57600 + (size_t)(r0 + lr0) * 60 + lane;
        ST(0,0);  ST(0,1);  ST(0,2);  ST(0,3);  ST(0,4);  ST(0,5);  ST(0,6);  ST(0,7);
        ST(0,8);  ST(0,9);  ST(0,10); ST(0,11); ST(0,12); ST(0,13); ST(0,14); ST(0,15);
        ST(1,0);  ST(1,1);  ST(1,2);  ST(1,3);  ST(1,4);  ST(1,5);  ST(1,6);  ST(1,7);
        ST(1,8);  ST(1,9);  ST(1,10); ST(1,11); ST(1,12); ST(1,13); ST(1,14); ST(1,15);
    }
}

extern "C" void kernel_launch(void* const* d_in, const int* in_sizes, int n_in,
                              void* d_out, int out_size, void* d_ws, size_t ws_size,
                              hipStream_t stream) {
    const float* x  = (const float*)d_in[0];
    const float* W  = (const float*)d_in[1];
    const float* b  = (const float*)d_in[2];
    float* out      = (float*)d_out;

    const int nimg = in_sizes[0] / (6 * 64 * 64);   // 2048
    dim3 grid(nimg * 5), block(THREADS);
    hipLaunchKernelGGL(c3_conv, grid, block, 0, stream, x, W, b, out);
}